// Round 1
// baseline (5621.766 us; speedup 1.0000x reference)
//
#include <hip/hip_runtime.h>
#include <hip/hip_bf16.h>
#include <math.h>

#define PI_F 3.14159265358979323846f

// ---------------------------------------------------------------------------
// Generic direct 3x3 conv, zero padding 1, fp32.
// Tile: TCO = 16*COPT output channels x 64 pixels (one row segment).
// Block 256 threads = 16 (co groups) x 16 (px groups), 4 px per thread
// (stride 16), COPT co per thread. Cin staged in chunks of 8 through LDS.
// ---------------------------------------------------------------------------
template<int COPT, bool RELU>
__global__ __launch_bounds__(256) void conv3x3_kernel(
    const float* __restrict__ in, const float* __restrict__ w,
    const float* __restrict__ bias, float* __restrict__ out,
    int Cin, int Cout, int H, int W)
{
    constexpr int TCO = 16 * COPT;
    const int tilesx = (W + 63) >> 6;
    const int y  = blockIdx.x / tilesx;
    const int x0 = (blockIdx.x % tilesx) << 6;
    const int co0 = blockIdx.y * TCO;
    const int t  = threadIdx.x;
    const int tr = t >> 4;   // 0..15 : co group
    const int tc = t & 15;   // 0..15 : px group

    __shared__ float sIn[8][3][66];
    __shared__ float sW[8][9][TCO];

    float acc[COPT][4];
#pragma unroll
    for (int i = 0; i < COPT; ++i)
#pragma unroll
        for (int j = 0; j < 4; ++j) acc[i][j] = 0.f;

    const int HWio = H * W;

    for (int ci0 = 0; ci0 < Cin; ci0 += 8) {
        __syncthreads();
        // stage input: 8 ci x 3 rows x 66 cols (zero-padded halo)
        for (int i = t; i < 8 * 198; i += 256) {
            int ciI = i / 198;
            int r   = (i % 198) / 66;
            int xx  = (i % 198) % 66;
            int ci = ci0 + ciI, gy = y + r - 1, gx = x0 + xx - 1;
            float v = 0.f;
            if (ci < Cin && gy >= 0 && gy < H && gx >= 0 && gx < W)
                v = in[ci * HWio + gy * W + gx];
            sIn[ciI][r][xx] = v;
        }
        // stage weights: 8 ci x 9 taps x TCO co (tap-major so A reads vectorize)
        for (int i = t; i < 8 * 9 * TCO; i += 256) {
            int ciI = i / (9 * TCO);
            int rem = i % (9 * TCO);
            int tap = rem / TCO;
            int coI = rem % TCO;
            int ci = ci0 + ciI, co = co0 + coI;
            float v = 0.f;
            if (ci < Cin && co < Cout) v = w[(co * Cin + ci) * 9 + tap];
            sW[ciI][tap][coI] = v;
        }
        __syncthreads();

#pragma unroll
        for (int ciI = 0; ciI < 8; ++ciI) {
#pragma unroll
            for (int dy = 0; dy < 3; ++dy) {
#pragma unroll
                for (int dx = 0; dx < 3; ++dx) {
                    float b0 = sIn[ciI][dy][tc +  0 + dx];
                    float b1 = sIn[ciI][dy][tc + 16 + dx];
                    float b2 = sIn[ciI][dy][tc + 32 + dx];
                    float b3 = sIn[ciI][dy][tc + 48 + dx];
#pragma unroll
                    for (int i = 0; i < COPT; ++i) {
                        float a = sW[ciI][dy * 3 + dx][tr * COPT + i];
                        acc[i][0] += a * b0;
                        acc[i][1] += a * b1;
                        acc[i][2] += a * b2;
                        acc[i][3] += a * b3;
                    }
                }
            }
        }
    }

#pragma unroll
    for (int i = 0; i < COPT; ++i) {
        int co = co0 + tr * COPT + i;
        if (co < Cout) {
            float bv = bias[co];
#pragma unroll
            for (int j = 0; j < 4; ++j) {
                int x = x0 + tc + 16 * j;
                if (x < W) {
                    float v = acc[i][j] + bv;
                    if (RELU) v = fmaxf(v, 0.f);
                    out[co * HWio + y * W + x] = v;
                }
            }
        }
    }
}

// ---------------------------------------------------------------------------
// Fused softmax over 225 psf taps + reflect-padded patch weighted sum.
// One thread per pixel; online (rescaled) softmax, single pass over logits.
// ---------------------------------------------------------------------------
__global__ __launch_bounds__(256) void softmax_patch_kernel(
    const float* __restrict__ logits,   // [225][65536]
    const float* __restrict__ rawc,     // raw channel base [256][256]
    float* __restrict__ corr)           // corrected channel base [256][256]
{
    int p = blockIdx.x * 256 + threadIdx.x;
    int y = p >> 8, x = p & 255;
    float m = -1e30f, s = 0.f, acc = 0.f;
    int tt = 0;
    for (int ty = 0; ty < 15; ++ty) {
        int gy = y + ty - 7;
        gy = gy < 0 ? -gy : (gy > 255 ? 510 - gy : gy);
        const float* rrow = rawc + gy * 256;
        for (int tx = 0; tx < 15; ++tx, ++tt) {
            int gx = x + tx - 7;
            gx = gx < 0 ? -gx : (gx > 255 ? 510 - gx : gx);
            float l  = logits[tt * 65536 + p];
            float pv = rrow[gx];
            float mn = fmaxf(m, l);
            float sc = __expf(m - mn);
            float e  = __expf(l - mn);
            s   = s * sc + e;
            acc = acc * sc + e * pv;
            m = mn;
        }
    }
    corr[p] = acc / s;
}

// ---------------------------------------------------------------------------
// FFT via brute-force 256-point DFTs with LDS twiddle tables.
// rfft2(x, ortho): row real->complex DFT, then column complex DFT, scale 1/256.
// ---------------------------------------------------------------------------
__global__ __launch_bounds__(256) void rdft_row_kernel(
    const float* __restrict__ x, float2* __restrict__ z)
{
    int cy = blockIdx.x;               // c*256 + y
    __shared__ float row[256];
    __shared__ float ct[256], st[256];
    int t = threadIdx.x;
    row[t] = x[cy * 256 + t];
    float a = (2.0f * PI_F / 256.0f) * (float)t;
    ct[t] = cosf(a);
    st[t] = sinf(a);
    __syncthreads();
    if (t < 129) {
        float re = 0.f, im = 0.f;
        int idx = 0;
        for (int n = 0; n < 256; ++n) {
            float v = row[n];
            re += v * ct[idx];
            im -= v * st[idx];
            idx = (idx + t) & 255;
        }
        z[cy * 129 + t] = make_float2(re, im);
    }
}

__global__ __launch_bounds__(256) void dft_col_fwd_kernel(
    const float2* __restrict__ z, float* __restrict__ fri)
{
    int c  = blockIdx.x >> 8;
    int k1 = blockIdx.x & 255;
    __shared__ float ct[256], st[256];
    int t = threadIdx.x;
    float a = (2.0f * PI_F / 256.0f) * (float)t;
    ct[t] = cosf(a);
    st[t] = sinf(a);
    __syncthreads();
    if (t < 129) {
        float re = 0.f, im = 0.f;
        int idx = 0;
        for (int n1 = 0; n1 < 256; ++n1) {
            float2 zv = z[(c * 256 + n1) * 129 + t];
            float cw = ct[idx], sw = st[idx];
            re += zv.x * cw + zv.y * sw;   // * e^{-i theta}
            im += zv.y * cw - zv.x * sw;
            idx = (idx + k1) & 255;
        }
        const float sc = 1.0f / 256.0f;
        fri[(c * 256 + k1) * 129 + t]       = re * sc;
        fri[((4 + c) * 256 + k1) * 129 + t] = im * sc;
    }
}

// irfft2(cf, ortho): inverse DFT over k1 (complex), then Hermitian row
// inverse over k2 (imag of bins 0,128 discarded), total scale 1/256.
__global__ __launch_bounds__(256) void dft_col_inv_kernel(
    const float* __restrict__ g, float2* __restrict__ z)
{
    int c  = blockIdx.x >> 8;
    int n1 = blockIdx.x & 255;
    __shared__ float ct[256], st[256];
    int t = threadIdx.x;
    float a = (2.0f * PI_F / 256.0f) * (float)t;
    ct[t] = cosf(a);
    st[t] = sinf(a);
    __syncthreads();
    if (t < 129) {
        float re = 0.f, im = 0.f;
        int idx = 0;
        for (int k1 = 0; k1 < 256; ++k1) {
            float gr = g[(c * 256 + k1) * 129 + t];
            float gi = g[((4 + c) * 256 + k1) * 129 + t];
            float cw = ct[idx], sw = st[idx];
            re += gr * cw - gi * sw;       // * e^{+i theta}
            im += gi * cw + gr * sw;
            idx = (idx + n1) & 255;
        }
        z[(c * 256 + n1) * 129 + t] = make_float2(re, im);
    }
}

__global__ __launch_bounds__(256) void irdft_row_add_kernel(
    const float2* __restrict__ z, float* __restrict__ corrected)
{
    int c  = blockIdx.x >> 8;
    int n1 = blockIdx.x & 255;
    __shared__ float2 yrow[129];
    __shared__ float ct[256], st[256];
    int t = threadIdx.x;
    if (t < 129) yrow[t] = z[(c * 256 + n1) * 129 + t];
    float a = (2.0f * PI_F / 256.0f) * (float)t;
    ct[t] = cosf(a);
    st[t] = sinf(a);
    __syncthreads();
    // n2 = t
    float acc = yrow[0].x + ((t & 1) ? -yrow[128].x : yrow[128].x);
    int idx = t;   // k=1 twiddle index = n2
    for (int k = 1; k <= 127; ++k) {
        float2 yv = yrow[k];
        acc += 2.0f * (yv.x * ct[idx] - yv.y * st[idx]);
        idx = (idx + t) & 255;
    }
    corrected[c * 65536 + n1 * 256 + t] += acc * (1.0f / 256.0f);
}

// ---------------------------------------------------------------------------
__global__ __launch_bounds__(256) void final_clip_kernel(
    const float* __restrict__ raw, const float* __restrict__ refined,
    float* __restrict__ out)
{
    int i = blockIdx.x * 256 + threadIdx.x;
    float v = raw[i] + refined[i];
    out[i] = fminf(fmaxf(v, 0.f), 1.f);
}

// ---------------------------------------------------------------------------
extern "C" void kernel_launch(void* const* d_in, const int* in_sizes, int n_in,
                              void* d_out, int out_size, void* d_ws, size_t ws_size,
                              hipStream_t stream)
{
    const float* raw = (const float*)d_in[0];
    const float* ab  = (const float*)d_in[1];
    const float* pw1 = (const float*)d_in[2];  const float* pb1 = (const float*)d_in[3];
    const float* pw2 = (const float*)d_in[4];  const float* pb2 = (const float*)d_in[5];
    const float* pw3 = (const float*)d_in[6];  const float* pb3 = (const float*)d_in[7];
    const float* fw1 = (const float*)d_in[8];  const float* fb1 = (const float*)d_in[9];
    const float* fw2 = (const float*)d_in[10]; const float* fb2 = (const float*)d_in[11];
    const float* fw3 = (const float*)d_in[12]; const float* fb3 = (const float*)d_in[13];
    const float* cw1 = (const float*)d_in[14]; const float* cb1 = (const float*)d_in[15];
    const float* cw2 = (const float*)d_in[16]; const float* cb2 = (const float*)d_in[17];
    const float* cw3 = (const float*)d_in[18]; const float* cb3 = (const float*)d_in[19];
    float* out = (float*)d_out;

    float* Wf = (float*)d_ws;
    // region layout (floats):
    float* h1        = Wf;                   // 16,777,216  (also logits / g bufs / t bufs later)
    float* h2        = Wf + 16777216;        //  8,388,608  (also zbuf + fri later)
    float* corrected = Wf + 25165824;        //    262,144
    float* refined   = Wf + 25427968;        //    262,144
    float* logits = h1;
    float2* zbuf  = (float2*)h2;             // 264,192 float2 (= 528,384 floats)
    float* fri    = h2 + 1048576;            // 264,192 floats
    float* g1     = h1;                      // 2,113,536
    float* g2     = h1 + 2113536;            // 2,113,536
    float* gf     = h1 + 4227072;            //   264,192
    float* t1     = h1 + 4491264;            // 1,048,576
    float* t2     = h1 + 5539840;            // 1,048,576

    dim3 blk(256);

    // conv1: aberration_features (128) -> h1 (256), relu
    conv3x3_kernel<4, true><<<dim3(4 * 256, 4), blk, 0, stream>>>(
        ab, pw1, pb1, h1, 128, 256, 256, 256);
    // conv2: h1 (256) -> h2 (128), relu
    conv3x3_kernel<4, true><<<dim3(4 * 256, 2), blk, 0, stream>>>(
        h1, pw2, pb2, h2, 256, 128, 256, 256);
    // psf conv + fused softmax/patch-sum, one image channel at a time
    for (int c = 0; c < 4; ++c) {
        conv3x3_kernel<4, false><<<dim3(4 * 256, 4), blk, 0, stream>>>(
            h2, pw3 + (size_t)c * 225 * 128 * 9, pb3 + c * 225, logits,
            128, 225, 256, 256);
        softmax_patch_kernel<<<dim3(256), blk, 0, stream>>>(
            logits, raw + c * 65536, corrected + c * 65536);
    }
    // forward rfft2 (ortho)
    rdft_row_kernel<<<dim3(1024), blk, 0, stream>>>(corrected, zbuf);
    dft_col_fwd_kernel<<<dim3(1024), blk, 0, stream>>>(zbuf, fri);
    // freq-domain convs (H=256, W=129 -> 3 x-tiles)
    conv3x3_kernel<4, true><<<dim3(3 * 256, 1), blk, 0, stream>>>(
        fri, fw1, fb1, g1, 8, 64, 256, 129);
    conv3x3_kernel<4, true><<<dim3(3 * 256, 1), blk, 0, stream>>>(
        g1, fw2, fb2, g2, 64, 64, 256, 129);
    conv3x3_kernel<1, false><<<dim3(3 * 256, 1), blk, 0, stream>>>(
        g2, fw3, fb3, gf, 64, 8, 256, 129);
    // inverse irfft2 (ortho), accumulate into corrected
    dft_col_inv_kernel<<<dim3(1024), blk, 0, stream>>>(gf, zbuf);
    irdft_row_add_kernel<<<dim3(1024), blk, 0, stream>>>(zbuf, corrected);
    // per-channel refinement
    for (int c = 0; c < 4; ++c) {
        conv3x3_kernel<1, true><<<dim3(4 * 256, 1), blk, 0, stream>>>(
            corrected + c * 65536, cw1 + c * 144, cb1 + c * 16, t1,
            1, 16, 256, 256);
        conv3x3_kernel<1, true><<<dim3(4 * 256, 1), blk, 0, stream>>>(
            t1, cw2 + c * 2304, cb2 + c * 16, t2, 16, 16, 256, 256);
        conv3x3_kernel<1, false><<<dim3(4 * 256, 1), blk, 0, stream>>>(
            t2, cw3 + c * 144, cb3 + c, refined + c * 65536, 16, 1, 256, 256);
    }
    final_clip_kernel<<<dim3(1024), blk, 0, stream>>>(raw, refined, out);
}

// Round 2
// 1080.729 us; speedup vs baseline: 5.2018x; 5.2018x over previous
//
#include <hip/hip_runtime.h>
#include <hip/hip_bf16.h>
#include <math.h>

#define PI_F 3.14159265358979323846f

typedef short bfrag __attribute__((ext_vector_type(8)));   // 8 bf16 in 4 VGPRs
typedef float f32x4 __attribute__((ext_vector_type(4)));

__device__ inline unsigned bf16rne(float x) {
    unsigned u = __builtin_bit_cast(unsigned, x);
    return (u + 0x7fffu + ((u >> 16) & 1u)) >> 16;
}
__device__ inline unsigned packbf2(float a, float b) {
    return bf16rne(a) | (bf16rne(b) << 16);
}
// 16B-unit swizzle within one staged row: unit = px*4+g. XOR low bits with
// higher px bits -> ds_read_b128 frag reads and b32 staging writes both land
// ~2-way on banks (free per m136).
__device__ inline int swzu(int px, int g) {
    int u = (px << 2) | g;
    return u ^ ((px >> 1) & 3) ^ ((px >> 3) & 7);
}

// ---------------------------------------------------------------------------
// MFMA implicit-GEMM 3x3 conv, pad 1, fp32 NCHW in/out, bf16 operands.
// Block: 256 thr = 4 waves; tile 64 co x 128 px (one image row segment).
// Wave (wm,wn): 32 co x 64 px -> acc[2][4] 16x16 fragments.
// K loop: 9 taps x Cin/32 chunks; input chunk staged in LDS [136 px][32 ci]
// bf16 (3 rows incl. halo), swizzled; weights pre-packed in fragment order.
// ---------------------------------------------------------------------------
template<bool RELU>
__global__ __launch_bounds__(256) void conv3_mfma(
    const float* __restrict__ in, const short* __restrict__ wp,
    const float* __restrict__ bias, float* __restrict__ out,
    int Cin, int Cout, int CoutPad, int H, int W)
{
    const int HW = H * W;
    const int tilesx = W >> 7;
    const int y  = blockIdx.x / tilesx;
    const int x0 = (blockIdx.x % tilesx) << 7;
    const int co0 = blockIdx.y << 6;
    const int t = threadIdx.x;
    const int l15 = t & 15;
    const int lg  = (t >> 4) & 3;
    const int wv  = t >> 6;
    const int wm  = wv & 1, wn = wv >> 1;

    __shared__ __align__(16) unsigned char sB[3 * 8704];   // 3 rows x 136 px x 32 ci bf16

    f32x4 acc[2][4];
#pragma unroll
    for (int m = 0; m < 2; ++m)
#pragma unroll
        for (int n = 0; n < 4; ++n) acc[m][n] = (f32x4){0.f, 0.f, 0.f, 0.f};

    const int C32 = Cin >> 5;
    const int cA0 = (co0 + wm * 32 + l15) * 4 + lg;   // A-frag index (m=0)
    const int cA1 = cA0 + 64;                          // +16 co
    const bfrag* wpf = (const bfrag*)wp;
    const size_t tstride = (size_t)C32 * CoutPad * 4;  // per-tap frag stride

    for (int c32 = 0; c32 < C32; ++c32) {
        __syncthreads();
        // stage chunk: rows y-1..y+1, px slots 0..135 (gx = x0-4+slot), ci pairs
        for (int i = t; i < 816; i += 256) {
            int r  = i / 272, rem = i % 272;
            int cp = rem / 17, u8 = rem % 17;
            int ciL = cp * 2;
            int gy  = y + r - 1;
            int gx0 = x0 - 4 + u8 * 8;
            const float* pa = in + (size_t)(c32 * 32 + ciL) * HW + gy * W + gx0;
            const float* pb = pa + HW;
            float fa[8], fb[8];
            bool gyok = (unsigned)gy < (unsigned)H;
            if (gyok && gx0 >= 0 && gx0 + 8 <= W) {
                float4 a0 = *(const float4*)pa, a1 = *(const float4*)(pa + 4);
                float4 b0 = *(const float4*)pb, b1 = *(const float4*)(pb + 4);
                fa[0]=a0.x; fa[1]=a0.y; fa[2]=a0.z; fa[3]=a0.w;
                fa[4]=a1.x; fa[5]=a1.y; fa[6]=a1.z; fa[7]=a1.w;
                fb[0]=b0.x; fb[1]=b0.y; fb[2]=b0.z; fb[3]=b0.w;
                fb[4]=b1.x; fb[5]=b1.y; fb[6]=b1.z; fb[7]=b1.w;
            } else {
#pragma unroll
                for (int k = 0; k < 8; ++k) {
                    int gx = gx0 + k;
                    bool ok = gyok && (unsigned)gx < (unsigned)W;
                    fa[k] = ok ? pa[k] : 0.f;
                    fb[k] = ok ? pb[k] : 0.f;
                }
            }
            int g = ciL >> 3, bo = (ciL & 7) << 1;
            unsigned char* rowp = sB + r * 8704;
#pragma unroll
            for (int k = 0; k < 8; ++k)
                *(unsigned*)(rowp + swzu(u8 * 8 + k, g) * 16 + bo) = packbf2(fa[k], fb[k]);
        }
        __syncthreads();

        const size_t toff0 = (size_t)c32 * CoutPad * 4;
#pragma unroll
        for (int tap = 0; tap < 9; ++tap) {
            const int dy = tap / 3, dx = tap % 3;
            bfrag a0 = wpf[toff0 + (size_t)tap * tstride + cA0];
            bfrag a1 = wpf[toff0 + (size_t)tap * tstride + cA1];
            const unsigned char* rowp = sB + dy * 8704;
#pragma unroll
            for (int n = 0; n < 4; ++n) {
                int ps = (wn << 6) + (n << 4) + l15 + dx + 3;
                bfrag b = *(const bfrag*)(rowp + swzu(ps, lg) * 16);
                acc[0][n] = __builtin_amdgcn_mfma_f32_16x16x32_bf16(a0, b, acc[0][n], 0, 0, 0);
                acc[1][n] = __builtin_amdgcn_mfma_f32_16x16x32_bf16(a1, b, acc[1][n], 0, 0, 0);
            }
        }
    }

    // epilogue: C frag row = co = (lg*4+r), col = px = l15
#pragma unroll
    for (int m = 0; m < 2; ++m) {
        int cob = co0 + wm * 32 + m * 16 + lg * 4;
#pragma unroll
        for (int r = 0; r < 4; ++r) {
            int co = cob + r;
            if (co < Cout) {
                float bv = bias[co];
                float* op = out + (size_t)co * HW + y * W + x0 + (wn << 6) + l15;
#pragma unroll
                for (int n = 0; n < 4; ++n) {
                    float v = acc[m][n][r] + bv;
                    if (RELU) v = fmaxf(v, 0.f);
                    op[n << 4] = v;
                }
            }
        }
    }
}

// Repack fp32 OIHW weights -> bf16 fragment order:
// idx = ((tap*C32 + ci/32)*CoutPad + co)*32 + (ci&31)
__global__ __launch_bounds__(256) void repack_w(
    const float* __restrict__ w, unsigned short* __restrict__ o,
    int Cin, int Cout, int CoutPad)
{
    int C32 = Cin >> 5;
    int total = 9 * C32 * CoutPad * 32;
    for (int i = blockIdx.x * 256 + threadIdx.x; i < total; i += gridDim.x * 256) {
        int j = i & 31;
        int rest = i >> 5;
        int co = rest % CoutPad; rest /= CoutPad;
        int c32 = rest % C32;
        int tap = rest / C32;
        float v = 0.f;
        if (co < Cout) v = w[((size_t)co * Cin + c32 * 32 + j) * 9 + tap];
        o[i] = (unsigned short)bf16rne(v);
    }
}

// ---------------------------------------------------------------------------
// Generic direct 3x3 conv (fp32) — kept for the small convs.
// ---------------------------------------------------------------------------
template<int COPT, bool RELU>
__global__ __launch_bounds__(256) void conv3x3_kernel(
    const float* __restrict__ in, const float* __restrict__ w,
    const float* __restrict__ bias, float* __restrict__ out,
    int Cin, int Cout, int H, int W)
{
    constexpr int TCO = 16 * COPT;
    const int tilesx = (W + 63) >> 6;
    const int y  = blockIdx.x / tilesx;
    const int x0 = (blockIdx.x % tilesx) << 6;
    const int co0 = blockIdx.y * TCO;
    const int t  = threadIdx.x;
    const int tr = t >> 4;
    const int tc = t & 15;

    __shared__ float sIn[8][3][66];
    __shared__ float sW[8][9][TCO];

    float acc[COPT][4];
#pragma unroll
    for (int i = 0; i < COPT; ++i)
#pragma unroll
        for (int j = 0; j < 4; ++j) acc[i][j] = 0.f;

    const int HWio = H * W;

    for (int ci0 = 0; ci0 < Cin; ci0 += 8) {
        __syncthreads();
        for (int i = t; i < 8 * 198; i += 256) {
            int ciI = i / 198;
            int r   = (i % 198) / 66;
            int xx  = (i % 198) % 66;
            int ci = ci0 + ciI, gy = y + r - 1, gx = x0 + xx - 1;
            float v = 0.f;
            if (ci < Cin && gy >= 0 && gy < H && gx >= 0 && gx < W)
                v = in[ci * HWio + gy * W + gx];
            sIn[ciI][r][xx] = v;
        }
        for (int i = t; i < 8 * 9 * TCO; i += 256) {
            int ciI = i / (9 * TCO);
            int rem = i % (9 * TCO);
            int tap = rem / TCO;
            int coI = rem % TCO;
            int ci = ci0 + ciI, co = co0 + coI;
            float v = 0.f;
            if (ci < Cin && co < Cout) v = w[(co * Cin + ci) * 9 + tap];
            sW[ciI][tap][coI] = v;
        }
        __syncthreads();

#pragma unroll
        for (int ciI = 0; ciI < 8; ++ciI) {
#pragma unroll
            for (int dy = 0; dy < 3; ++dy) {
#pragma unroll
                for (int dx = 0; dx < 3; ++dx) {
                    float b0 = sIn[ciI][dy][tc +  0 + dx];
                    float b1 = sIn[ciI][dy][tc + 16 + dx];
                    float b2 = sIn[ciI][dy][tc + 32 + dx];
                    float b3 = sIn[ciI][dy][tc + 48 + dx];
#pragma unroll
                    for (int i = 0; i < COPT; ++i) {
                        float a = sW[ciI][dy * 3 + dx][tr * COPT + i];
                        acc[i][0] += a * b0;
                        acc[i][1] += a * b1;
                        acc[i][2] += a * b2;
                        acc[i][3] += a * b3;
                    }
                }
            }
        }
    }

#pragma unroll
    for (int i = 0; i < COPT; ++i) {
        int co = co0 + tr * COPT + i;
        if (co < Cout) {
            float bv = bias[co];
#pragma unroll
            for (int j = 0; j < 4; ++j) {
                int x = x0 + tc + 16 * j;
                if (x < W) {
                    float v = acc[i][j] + bv;
                    if (RELU) v = fmaxf(v, 0.f);
                    out[co * HWio + y * W + x] = v;
                }
            }
        }
    }
}

// ---------------------------------------------------------------------------
// Fused softmax over 225 psf taps + reflect-padded patch weighted sum.
// ---------------------------------------------------------------------------
__global__ __launch_bounds__(256) void softmax_patch_kernel(
    const float* __restrict__ logits,
    const float* __restrict__ rawc,
    float* __restrict__ corr)
{
    int p = blockIdx.x * 256 + threadIdx.x;
    int y = p >> 8, x = p & 255;
    float m = -1e30f, s = 0.f, acc = 0.f;
    int tt = 0;
    for (int ty = 0; ty < 15; ++ty) {
        int gy = y + ty - 7;
        gy = gy < 0 ? -gy : (gy > 255 ? 510 - gy : gy);
        const float* rrow = rawc + gy * 256;
        for (int tx = 0; tx < 15; ++tx, ++tt) {
            int gx = x + tx - 7;
            gx = gx < 0 ? -gx : (gx > 255 ? 510 - gx : gx);
            float l  = logits[tt * 65536 + p];
            float pv = rrow[gx];
            float mn = fmaxf(m, l);
            float sc = __expf(m - mn);
            float e  = __expf(l - mn);
            s   = s * sc + e;
            acc = acc * sc + e * pv;
            m = mn;
        }
    }
    corr[p] = acc / s;
}

// ---------------------------------------------------------------------------
// Brute-force 256-pt DFT kernels (ortho rfft2 / irfft2)
// ---------------------------------------------------------------------------
__global__ __launch_bounds__(256) void rdft_row_kernel(
    const float* __restrict__ x, float2* __restrict__ z)
{
    int cy = blockIdx.x;
    __shared__ float row[256];
    __shared__ float ct[256], st[256];
    int t = threadIdx.x;
    row[t] = x[cy * 256 + t];
    float a = (2.0f * PI_F / 256.0f) * (float)t;
    ct[t] = cosf(a);
    st[t] = sinf(a);
    __syncthreads();
    if (t < 129) {
        float re = 0.f, im = 0.f;
        int idx = 0;
        for (int n = 0; n < 256; ++n) {
            float v = row[n];
            re += v * ct[idx];
            im -= v * st[idx];
            idx = (idx + t) & 255;
        }
        z[cy * 129 + t] = make_float2(re, im);
    }
}

__global__ __launch_bounds__(256) void dft_col_fwd_kernel(
    const float2* __restrict__ z, float* __restrict__ fri)
{
    int c  = blockIdx.x >> 8;
    int k1 = blockIdx.x & 255;
    __shared__ float ct[256], st[256];
    int t = threadIdx.x;
    float a = (2.0f * PI_F / 256.0f) * (float)t;
    ct[t] = cosf(a);
    st[t] = sinf(a);
    __syncthreads();
    if (t < 129) {
        float re = 0.f, im = 0.f;
        int idx = 0;
        for (int n1 = 0; n1 < 256; ++n1) {
            float2 zv = z[(c * 256 + n1) * 129 + t];
            float cw = ct[idx], sw = st[idx];
            re += zv.x * cw + zv.y * sw;
            im += zv.y * cw - zv.x * sw;
            idx = (idx + k1) & 255;
        }
        const float sc = 1.0f / 256.0f;
        fri[(c * 256 + k1) * 129 + t]       = re * sc;
        fri[((4 + c) * 256 + k1) * 129 + t] = im * sc;
    }
}

__global__ __launch_bounds__(256) void dft_col_inv_kernel(
    const float* __restrict__ g, float2* __restrict__ z)
{
    int c  = blockIdx.x >> 8;
    int n1 = blockIdx.x & 255;
    __shared__ float ct[256], st[256];
    int t = threadIdx.x;
    float a = (2.0f * PI_F / 256.0f) * (float)t;
    ct[t] = cosf(a);
    st[t] = sinf(a);
    __syncthreads();
    if (t < 129) {
        float re = 0.f, im = 0.f;
        int idx = 0;
        for (int k1 = 0; k1 < 256; ++k1) {
            float gr = g[(c * 256 + k1) * 129 + t];
            float gi = g[((4 + c) * 256 + k1) * 129 + t];
            float cw = ct[idx], sw = st[idx];
            re += gr * cw - gi * sw;
            im += gi * cw + gr * sw;
            idx = (idx + n1) & 255;
        }
        z[(c * 256 + n1) * 129 + t] = make_float2(re, im);
    }
}

__global__ __launch_bounds__(256) void irdft_row_add_kernel(
    const float2* __restrict__ z, float* __restrict__ corrected)
{
    int c  = blockIdx.x >> 8;
    int n1 = blockIdx.x & 255;
    __shared__ float2 yrow[129];
    __shared__ float ct[256], st[256];
    int t = threadIdx.x;
    if (t < 129) yrow[t] = z[(c * 256 + n1) * 129 + t];
    float a = (2.0f * PI_F / 256.0f) * (float)t;
    ct[t] = cosf(a);
    st[t] = sinf(a);
    __syncthreads();
    float acc = yrow[0].x + ((t & 1) ? -yrow[128].x : yrow[128].x);
    int idx = t;
    for (int k = 1; k <= 127; ++k) {
        float2 yv = yrow[k];
        acc += 2.0f * (yv.x * ct[idx] - yv.y * st[idx]);
        idx = (idx + t) & 255;
    }
    corrected[c * 65536 + n1 * 256 + t] += acc * (1.0f / 256.0f);
}

__global__ __launch_bounds__(256) void final_clip_kernel(
    const float* __restrict__ raw, const float* __restrict__ refined,
    float* __restrict__ out)
{
    int i = blockIdx.x * 256 + threadIdx.x;
    float v = raw[i] + refined[i];
    out[i] = fminf(fmaxf(v, 0.f), 1.f);
}

// ---------------------------------------------------------------------------
extern "C" void kernel_launch(void* const* d_in, const int* in_sizes, int n_in,
                              void* d_out, int out_size, void* d_ws, size_t ws_size,
                              hipStream_t stream)
{
    const float* raw = (const float*)d_in[0];
    const float* ab  = (const float*)d_in[1];
    const float* pw1 = (const float*)d_in[2];  const float* pb1 = (const float*)d_in[3];
    const float* pw2 = (const float*)d_in[4];  const float* pb2 = (const float*)d_in[5];
    const float* pw3 = (const float*)d_in[6];  const float* pb3 = (const float*)d_in[7];
    const float* fw1 = (const float*)d_in[8];  const float* fb1 = (const float*)d_in[9];
    const float* fw2 = (const float*)d_in[10]; const float* fb2 = (const float*)d_in[11];
    const float* fw3 = (const float*)d_in[12]; const float* fb3 = (const float*)d_in[13];
    const float* cw1 = (const float*)d_in[14]; const float* cb1 = (const float*)d_in[15];
    const float* cw2 = (const float*)d_in[16]; const float* cb2 = (const float*)d_in[17];
    const float* cw3 = (const float*)d_in[18]; const float* cb3 = (const float*)d_in[19];
    float* out = (float*)d_out;

    float* Wf = (float*)d_ws;
    float* h1        = Wf;                   // 16,777,216 f
    float* h2        = Wf + 16777216;        //  8,388,608 f
    float* corrected = Wf + 25165824;        //    262,144
    float* refined   = Wf + 25427968;        //    262,144
    float* logits = h1;
    float2* zbuf  = (float2*)h2;
    float* fri    = h2 + 1048576;
    float* g1     = h1;
    float* g2     = h1 + 2113536;
    float* gf     = h1 + 4227072;
    float* t1     = h1 + 4491264;
    float* t2     = h1 + 5539840;
    // packed weights (bf16) after round-1 regions
    unsigned short* wp1 = (unsigned short*)(Wf + 25690112);        // 294,912
    unsigned short* wp2 = wp1 + 294912;                            // 294,912
    unsigned short* wp3 = wp2 + 294912;                            // 4 x 294,912

    dim3 blk(256);

    // weight repacks
    repack_w<<<dim3(288), blk, 0, stream>>>(pw1, wp1, 128, 256, 256);
    repack_w<<<dim3(288), blk, 0, stream>>>(pw2, wp2, 256, 128, 128);
    for (int c = 0; c < 4; ++c)
        repack_w<<<dim3(288), blk, 0, stream>>>(
            pw3 + (size_t)c * 225 * 128 * 9, wp3 + (size_t)c * 294912, 128, 225, 256);

    // conv1: ab(128) -> h1(256), relu
    conv3_mfma<true><<<dim3(512, 4), blk, 0, stream>>>(
        ab, (const short*)wp1, pb1, h1, 128, 256, 256, 256, 256);
    // conv2: h1(256) -> h2(128), relu
    conv3_mfma<true><<<dim3(512, 2), blk, 0, stream>>>(
        h1, (const short*)wp2, pb2, h2, 256, 128, 128, 256, 256);
    // psf conv + fused softmax/patch-sum per image channel
    for (int c = 0; c < 4; ++c) {
        conv3_mfma<false><<<dim3(512, 4), blk, 0, stream>>>(
            h2, (const short*)(wp3 + (size_t)c * 294912), pb3 + c * 225, logits,
            128, 225, 256, 256, 256);
        softmax_patch_kernel<<<dim3(256), blk, 0, stream>>>(
            logits, raw + c * 65536, corrected + c * 65536);
    }
    // forward rfft2 (ortho)
    rdft_row_kernel<<<dim3(1024), blk, 0, stream>>>(corrected, zbuf);
    dft_col_fwd_kernel<<<dim3(1024), blk, 0, stream>>>(zbuf, fri);
    // freq-domain convs (H=256, W=129)
    conv3x3_kernel<4, true><<<dim3(3 * 256, 1), blk, 0, stream>>>(
        fri, fw1, fb1, g1, 8, 64, 256, 129);
    conv3x3_kernel<4, true><<<dim3(3 * 256, 1), blk, 0, stream>>>(
        g1, fw2, fb2, g2, 64, 64, 256, 129);
    conv3x3_kernel<1, false><<<dim3(3 * 256, 1), blk, 0, stream>>>(
        g2, fw3, fb3, gf, 64, 8, 256, 129);
    // inverse irfft2 (ortho), accumulate into corrected
    dft_col_inv_kernel<<<dim3(1024), blk, 0, stream>>>(gf, zbuf);
    irdft_row_add_kernel<<<dim3(1024), blk, 0, stream>>>(zbuf, corrected);
    // per-channel refinement
    for (int c = 0; c < 4; ++c) {
        conv3x3_kernel<1, true><<<dim3(4 * 256, 1), blk, 0, stream>>>(
            corrected + c * 65536, cw1 + c * 144, cb1 + c * 16, t1,
            1, 16, 256, 256);
        conv3x3_kernel<1, true><<<dim3(4 * 256, 1), blk, 0, stream>>>(
            t1, cw2 + c * 2304, cb2 + c * 16, t2, 16, 16, 256, 256);
        conv3x3_kernel<1, false><<<dim3(4 * 256, 1), blk, 0, stream>>>(
            t2, cw3 + c * 144, cb3 + c, refined + c * 65536, 16, 1, 256, 256);
    }
    final_clip_kernel<<<dim3(1024), blk, 0, stream>>>(raw, refined, out);
}

// Round 4
// 880.423 us; speedup vs baseline: 6.3853x; 1.2275x over previous
//
#include <hip/hip_runtime.h>
#include <hip/hip_bf16.h>
#include <math.h>

#define PI_F 3.14159265358979323846f

typedef short bfrag __attribute__((ext_vector_type(8)));   // 8 bf16 in 4 VGPRs
typedef float f32x4 __attribute__((ext_vector_type(4)));
typedef unsigned short us8 __attribute__((ext_vector_type(8)));

__device__ inline unsigned bf16rne(float x) {
    unsigned u = __builtin_bit_cast(unsigned, x);
    return (u + 0x7fffu + ((u >> 16) & 1u)) >> 16;
}
__device__ inline unsigned packbf2(float a, float b) {
    return bf16rne(a) | (bf16rne(b) << 16);
}
__device__ inline float bf2f(unsigned short u) {
    return __builtin_bit_cast(float, (unsigned)u << 16);
}
// 16B-unit swizzle (conv3_mfma staging)
__device__ inline int swzu(int px, int g) {
    int u = (px << 2) | g;
    return u ^ ((px >> 1) & 3) ^ ((px >> 3) & 7);
}

// ---------------------------------------------------------------------------
// MFMA implicit-GEMM 3x3 conv, pad 1, fp32 NCHW in/out (row stride RS), bf16.
// Tile 64 co x 128 px; 4 waves; LDS-staged input chunk of 32 ci.
// ---------------------------------------------------------------------------
template<bool RELU>
__global__ __launch_bounds__(256) void conv3_mfma(
    const float* __restrict__ in, const short* __restrict__ wp,
    const float* __restrict__ bias, float* __restrict__ out,
    int Cin, int Cout, int CoutPad, int H, int W, int RS)
{
    const size_t HRS = (size_t)H * RS;
    const int tilesx = (W + 127) >> 7;
    const int y  = blockIdx.x / tilesx;
    const int x0 = (blockIdx.x % tilesx) << 7;
    const int co0 = blockIdx.y << 6;
    const int t = threadIdx.x;
    const int l15 = t & 15;
    const int lg  = (t >> 4) & 3;
    const int wv  = t >> 6;
    const int wm  = wv & 1, wn = wv >> 1;

    __shared__ __align__(16) unsigned char sB[3 * 8704];   // 3 rows x 136 px x 32 ci bf16

    f32x4 acc[2][4];
#pragma unroll
    for (int m = 0; m < 2; ++m)
#pragma unroll
        for (int n = 0; n < 4; ++n) acc[m][n] = (f32x4){0.f, 0.f, 0.f, 0.f};

    const int C32 = Cin >> 5;
    const int cA0 = (co0 + wm * 32 + l15) * 4 + lg;
    const int cA1 = cA0 + 64;
    const bfrag* wpf = (const bfrag*)wp;
    const size_t tstride = (size_t)C32 * CoutPad * 4;

    for (int c32 = 0; c32 < C32; ++c32) {
        __syncthreads();
        for (int i = t; i < 816; i += 256) {
            int r  = i / 272, rem = i % 272;
            int cp = rem / 17, u8 = rem % 17;
            int ciL = cp * 2;
            int gy  = y + r - 1;
            int gx0 = x0 - 4 + u8 * 8;
            const float* pa = in + (size_t)(c32 * 32 + ciL) * HRS + (size_t)gy * RS + gx0;
            const float* pb = pa + HRS;
            float fa[8], fb[8];
            bool gyok = (unsigned)gy < (unsigned)H;
            if (gyok && gx0 >= 0 && gx0 + 8 <= W) {
                float4 a0 = *(const float4*)pa, a1 = *(const float4*)(pa + 4);
                float4 b0 = *(const float4*)pb, b1 = *(const float4*)(pb + 4);
                fa[0]=a0.x; fa[1]=a0.y; fa[2]=a0.z; fa[3]=a0.w;
                fa[4]=a1.x; fa[5]=a1.y; fa[6]=a1.z; fa[7]=a1.w;
                fb[0]=b0.x; fb[1]=b0.y; fb[2]=b0.z; fb[3]=b0.w;
                fb[4]=b1.x; fb[5]=b1.y; fb[6]=b1.z; fb[7]=b1.w;
            } else {
#pragma unroll
                for (int k = 0; k < 8; ++k) {
                    int gx = gx0 + k;
                    bool ok = gyok && (unsigned)gx < (unsigned)W;
                    fa[k] = ok ? pa[k] : 0.f;
                    fb[k] = ok ? pb[k] : 0.f;
                }
            }
            int g = ciL >> 3, bo = (ciL & 7) << 1;
            unsigned char* rowp = sB + r * 8704;
#pragma unroll
            for (int k = 0; k < 8; ++k)
                *(unsigned*)(rowp + swzu(u8 * 8 + k, g) * 16 + bo) = packbf2(fa[k], fb[k]);
        }
        __syncthreads();

        const size_t toff0 = (size_t)c32 * CoutPad * 4;
#pragma unroll
        for (int tap = 0; tap < 9; ++tap) {
            const int dy = tap / 3, dx = tap % 3;
            bfrag a0 = wpf[toff0 + (size_t)tap * tstride + cA0];
            bfrag a1 = wpf[toff0 + (size_t)tap * tstride + cA1];
            const unsigned char* rowp = sB + dy * 8704;
#pragma unroll
            for (int n = 0; n < 4; ++n) {
                int ps = (wn << 6) + (n << 4) + l15 + dx + 3;
                bfrag b = *(const bfrag*)(rowp + swzu(ps, lg) * 16);
                acc[0][n] = __builtin_amdgcn_mfma_f32_16x16x32_bf16(a0, b, acc[0][n], 0, 0, 0);
                acc[1][n] = __builtin_amdgcn_mfma_f32_16x16x32_bf16(a1, b, acc[1][n], 0, 0, 0);
            }
        }
    }

#pragma unroll
    for (int m = 0; m < 2; ++m) {
        int cob = co0 + wm * 32 + m * 16 + lg * 4;
#pragma unroll
        for (int r = 0; r < 4; ++r) {
            int co = cob + r;
            if (co < Cout) {
                float bv = bias[co];
                float* op = out + (size_t)co * HRS + (size_t)y * RS + x0 + (wn << 6) + l15;
#pragma unroll
                for (int n = 0; n < 4; ++n) {
                    int x = x0 + (wn << 6) + (n << 4) + l15;
                    if (x < W) {
                        float v = acc[m][n][r] + bv;
                        if (RELU) v = fmaxf(v, 0.f);
                        op[n << 4] = v;
                    }
                }
            }
        }
    }
}

// Repack fp32 OIHW -> bf16 frag order; CinPad >= Cin (zeros beyond).
__global__ __launch_bounds__(256) void repack_w(
    const float* __restrict__ w, unsigned short* __restrict__ o,
    int Cin, int CinPad, int Cout, int CoutPad)
{
    int C32 = CinPad >> 5;
    int total = 9 * C32 * CoutPad * 32;
    for (int i = blockIdx.x * 256 + threadIdx.x; i < total; i += gridDim.x * 256) {
        int j = i & 31;
        int rest = i >> 5;
        int co = rest % CoutPad; rest /= CoutPad;
        int c32 = rest % C32;
        int tap = rest / C32;
        int ci = c32 * 32 + j;
        float v = 0.f;
        if (co < Cout && ci < Cin) v = w[((size_t)co * Cin + ci) * 9 + tap];
        o[i] = (unsigned short)bf16rne(v);
    }
}

// Repack refinement conv2 weights: [4ch][5kt][16co][32k] bf16
// k<16 -> tap=2kt, ci=k ; k>=16 -> tap=2kt+1, ci=k-16 ; tap 9 -> 0
__global__ __launch_bounds__(256) void repack_wr2(
    const float* __restrict__ cw2, unsigned short* __restrict__ o)
{
    int i = blockIdx.x * 256 + threadIdx.x;
    if (i >= 10240) return;
    int k = i & 31, rest = i >> 5;
    int co = rest & 15;
    int kt = (rest >> 4) % 5;
    int ch = rest / 80;
    int tap = 2 * kt + (k >= 16 ? 1 : 0), ci = k & 15;
    float v = 0.f;
    if (tap < 9) v = cw2[(((size_t)ch * 16 + co) * 16 + ci) * 9 + tap];
    o[i] = (unsigned short)bf16rne(v);
}

// ---------------------------------------------------------------------------
// Refinement stage 1: per-channel 1->16 conv + relu, bf16 out [c][y][x][16ci]
// ---------------------------------------------------------------------------
__global__ __launch_bounds__(256) void refine1_kernel(
    const float* __restrict__ corrected, const float* __restrict__ cw1,
    const float* __restrict__ cb1, unsigned short* __restrict__ h1b)
{
    const int c = blockIdx.x >> 8;
    const int y = blockIdx.x & 255;
    const int t = threadIdx.x;
    __shared__ float sIn[3][258];
    __shared__ float sW[144];
    __shared__ float sBv[16];
    if (t < 144) sW[t] = cw1[c * 144 + t];
    if (t >= 144 && t < 160) sBv[t - 144] = cb1[c * 16 + (t - 144)];
    for (int i = t; i < 774; i += 256) {
        int r = i / 258, xx = i % 258;
        int gy = y + r - 1, gx = xx - 1;
        sIn[r][xx] = ((unsigned)gy < 256u && (unsigned)gx < 256u)
                   ? corrected[((size_t)c * 256 + gy) * 256 + gx] : 0.f;
    }
    __syncthreads();
    float a[9];
#pragma unroll
    for (int dy = 0; dy < 3; ++dy)
#pragma unroll
        for (int dx = 0; dx < 3; ++dx) a[dy * 3 + dx] = sIn[dy][t + dx];
    unsigned short ov[16];
#pragma unroll
    for (int co = 0; co < 16; ++co) {
        float acc = sBv[co];
#pragma unroll
        for (int tap = 0; tap < 9; ++tap) acc += a[tap] * sW[co * 9 + tap];
        acc = fmaxf(acc, 0.f);
        ov[co] = (unsigned short)bf16rne(acc);
    }
    unsigned short* op = h1b + ((((size_t)c * 256 + y) * 256 + t) << 4);
    *(uint4*)op = *(uint4*)ov;
    *(uint4*)(op + 8) = *(uint4*)(ov + 8);
}

// ---------------------------------------------------------------------------
// Refinement stage 2: 16->16 conv + relu via MFMA (M=16, K=160 incl pad).
// One block per (c,row); 4 waves x 64 px. bf16 in/out [c][y][x][16].
// ---------------------------------------------------------------------------
__global__ __launch_bounds__(256) void refine2_mfma(
    const unsigned short* __restrict__ h1b, const unsigned short* __restrict__ wr2,
    const float* __restrict__ cb2, unsigned short* __restrict__ h2b)
{
    const int c = blockIdx.x >> 8;
    const int y = blockIdx.x & 255;
    const int t = threadIdx.x;
    const int l15 = t & 15, lg = (t >> 4) & 3, wv = t >> 6;

    __shared__ __align__(16) unsigned char sA[3 * 258 * 32];

    for (int i = t; i < 1548; i += 256) {
        int r = i / 516, u = i % 516;
        int px = u >> 1, half = u & 1;
        int gy = y + r - 1, gx = px - 1;
        uint4 v = make_uint4(0, 0, 0, 0);
        if ((unsigned)gy < 256u && (unsigned)gx < 256u)
            v = *(const uint4*)(h1b + ((((size_t)c * 256 + gy) * 256 + gx) << 4) + (half << 3));
        *(uint4*)(sA + r * 8256 + px * 32 + ((half ^ ((px >> 2) & 1)) << 4)) = v;
    }
    __syncthreads();

    f32x4 acc[4];
#pragma unroll
    for (int n = 0; n < 4; ++n) acc[n] = (f32x4){0.f, 0.f, 0.f, 0.f};
    const bfrag* wf = (const bfrag*)(wr2 + (size_t)c * 2560);
    const int strip = wv * 64;
#pragma unroll
    for (int kt = 0; kt < 5; ++kt) {
        bfrag a = wf[(kt * 16 + l15) * 4 + lg];
        int tap1 = 2 * kt + 1; if (tap1 > 8) tap1 = 8;
        int tap = (lg < 2) ? (2 * kt) : tap1;
        int dy = tap / 3, dx = tap % 3;
#pragma unroll
        for (int n = 0; n < 4; ++n) {
            int pxs = strip + n * 16 + l15 + dx;
            bfrag b = *(const bfrag*)(sA + dy * 8256 + pxs * 32 +
                                      (((lg & 1) ^ ((pxs >> 2) & 1)) << 4));
            acc[n] = __builtin_amdgcn_mfma_f32_16x16x32_bf16(a, b, acc[n], 0, 0, 0);
        }
    }

#pragma unroll
    for (int n = 0; n < 4; ++n) {
        int px = strip + n * 16 + l15;
        unsigned short ov[4];
#pragma unroll
        for (int r = 0; r < 4; ++r) {
            int co = lg * 4 + r;
            float v = acc[n][r] + cb2[c * 16 + co];
            v = fmaxf(v, 0.f);
            ov[r] = (unsigned short)bf16rne(v);
        }
        *(ushort4*)(h2b + ((((size_t)c * 256 + y) * 256 + px) << 4) + lg * 4) = *(ushort4*)ov;
    }
}

// ---------------------------------------------------------------------------
// Refinement stage 3: 16->1 conv + add raw + clip -> out. Fused final stage.
// ---------------------------------------------------------------------------
__global__ __launch_bounds__(256) void refine3_kernel(
    const unsigned short* __restrict__ h2b, const float* __restrict__ cw3,
    const float* __restrict__ cb3, const float* __restrict__ raw,
    float* __restrict__ out)
{
    const int c = blockIdx.x >> 8;
    const int y = blockIdx.x & 255;
    const int t = threadIdx.x;
    __shared__ __align__(16) unsigned char sA[3 * 258 * 32];
    __shared__ float sW[144];
    if (t < 144) sW[t] = cw3[c * 144 + t];   // [ci][tap]
    for (int i = t; i < 1548; i += 256) {
        int r = i / 516, u = i % 516;
        int px = u >> 1, half = u & 1;
        int gy = y + r - 1, gx = px - 1;
        uint4 v = make_uint4(0, 0, 0, 0);
        if ((unsigned)gy < 256u && (unsigned)gx < 256u)
            v = *(const uint4*)(h2b + ((((size_t)c * 256 + gy) * 256 + gx) << 4) + (half << 3));
        *(uint4*)(sA + r * 8256 + px * 32 + ((half ^ ((px >> 2) & 1)) << 4)) = v;
    }
    __syncthreads();
    float acc = cb3[c];
#pragma unroll
    for (int tap = 0; tap < 9; ++tap) {
        int dy = tap / 3, dx = tap % 3;
        int px = t + dx;
        const unsigned char* p = sA + dy * 8256 + px * 32;
        int sw = ((px >> 2) & 1) << 4;
        us8 h0 = *(const us8*)(p + (sw ^ 0));
        us8 h1 = *(const us8*)(p + (sw ^ 16));
#pragma unroll
        for (int j = 0; j < 8; ++j) acc += bf2f(h0[j]) * sW[j * 9 + tap];
#pragma unroll
        for (int j = 0; j < 8; ++j) acc += bf2f(h1[j]) * sW[(8 + j) * 9 + tap];
    }
    size_t idx = ((size_t)c * 256 + y) * 256 + t;
    float v = raw[idx] + acc;
    out[idx] = fminf(fmaxf(v, 0.f), 1.f);
}

// ---------------------------------------------------------------------------
// Fused softmax(225) + reflect-patch weighted sum; 4 tap-subsets per px,
// exact online-softmax merge. Block = 64 px x 4 subsets.
// ---------------------------------------------------------------------------
__global__ __launch_bounds__(256) void softmax_patch_kernel(
    const float* __restrict__ logits,
    const float* __restrict__ rawc,
    float* __restrict__ corr)
{
    const int t = threadIdx.x;
    const int sub = t >> 6, pl = t & 63;
    const int p = blockIdx.x * 64 + pl;
    const int y = p >> 8, x = p & 255;
    __shared__ float sm[256], ss[256], sa[256];

    int start = sub * 56 + (sub > 0 ? 1 : 0);
    int count = (sub == 0) ? 57 : 56;
    float m = -1e30f, s = 0.f, acc = 0.f;
    for (int k = 0; k < count; ++k) {
        int tt = start + k;
        int ty = tt / 15, tx = tt - ty * 15;
        int gy = y + ty - 7;
        gy = gy < 0 ? -gy : (gy > 255 ? 510 - gy : gy);
        int gx = x + tx - 7;
        gx = gx < 0 ? -gx : (gx > 255 ? 510 - gx : gx);
        float l  = logits[(size_t)tt * 65536 + p];
        float pv = rawc[gy * 256 + gx];
        float mn = fmaxf(m, l);
        float sc = __expf(m - mn);
        float e  = __expf(l - mn);
        s   = s * sc + e;
        acc = acc * sc + e * pv;
        m = mn;
    }
    sm[t] = m; ss[t] = s; sa[t] = acc;
    __syncthreads();
    if (t < 64) {
#pragma unroll
        for (int i = 1; i < 4; ++i) {
            float mi = sm[i * 64 + t], si = ss[i * 64 + t], ai = sa[i * 64 + t];
            float M = fmaxf(m, mi);
            float sc0 = __expf(m - M), sc1 = __expf(mi - M);
            s = s * sc0 + si * sc1;
            acc = acc * sc0 + ai * sc1;
            m = M;
        }
        corr[p] = acc / s;
    }
}

// ---------------------------------------------------------------------------
// Brute-force 256-pt DFT kernels (ortho rfft2 / irfft2)
// ---------------------------------------------------------------------------
__global__ __launch_bounds__(256) void rdft_row_kernel(
    const float* __restrict__ x, float2* __restrict__ z)
{
    int cy = blockIdx.x;
    __shared__ float row[256];
    __shared__ float ct[256], st[256];
    int t = threadIdx.x;
    row[t] = x[cy * 256 + t];
    float a = (2.0f * PI_F / 256.0f) * (float)t;
    ct[t] = cosf(a);
    st[t] = sinf(a);
    __syncthreads();
    if (t < 129) {
        float re = 0.f, im = 0.f;
        int idx = 0;
        for (int n = 0; n < 256; ++n) {
            float v = row[n];
            re += v * ct[idx];
            im -= v * st[idx];
            idx = (idx + t) & 255;
        }
        z[cy * 129 + t] = make_float2(re, im);
    }
}

// writes into 32-channel padded fri (RS=132); re -> ch c, im -> ch 4+c
__global__ __launch_bounds__(256) void dft_col_fwd_kernel(
    const float2* __restrict__ z, float* __restrict__ fri32)
{
    int c  = blockIdx.x >> 8;
    int k1 = blockIdx.x & 255;
    __shared__ float ct[256], st[256];
    int t = threadIdx.x;
    float a = (2.0f * PI_F / 256.0f) * (float)t;
    ct[t] = cosf(a);
    st[t] = sinf(a);
    __syncthreads();
    if (t < 129) {
        float re = 0.f, im = 0.f;
        int idx = 0;
        for (int n1 = 0; n1 < 256; ++n1) {
            float2 zv = z[(c * 256 + n1) * 129 + t];
            float cw = ct[idx], sw = st[idx];
            re += zv.x * cw + zv.y * sw;
            im += zv.y * cw - zv.x * sw;
            idx = (idx + k1) & 255;
        }
        const float sc = 1.0f / 256.0f;
        fri32[((size_t)c * 256 + k1) * 132 + t]       = re * sc;
        fri32[((size_t)(4 + c) * 256 + k1) * 132 + t] = im * sc;
    }
}

// reads gf with RS=132 (ch 0..3 real, 4..7 imag)
__global__ __launch_bounds__(256) void dft_col_inv_kernel(
    const float* __restrict__ g, float2* __restrict__ z)
{
    int c  = blockIdx.x >> 8;
    int n1 = blockIdx.x & 255;
    __shared__ float ct[256], st[256];
    int t = threadIdx.x;
    float a = (2.0f * PI_F / 256.0f) * (float)t;
    ct[t] = cosf(a);
    st[t] = sinf(a);
    __syncthreads();
    if (t < 129) {
        float re = 0.f, im = 0.f;
        int idx = 0;
        for (int k1 = 0; k1 < 256; ++k1) {
            float gr = g[((size_t)c * 256 + k1) * 132 + t];
            float gi = g[((size_t)(4 + c) * 256 + k1) * 132 + t];
            float cw = ct[idx], sw = st[idx];
            re += gr * cw - gi * sw;
            im += gi * cw + gr * sw;
            idx = (idx + n1) & 255;
        }
        z[(c * 256 + n1) * 129 + t] = make_float2(re, im);
    }
}

__global__ __launch_bounds__(256) void irdft_row_add_kernel(
    const float2* __restrict__ z, float* __restrict__ corrected)
{
    int c  = blockIdx.x >> 8;
    int n1 = blockIdx.x & 255;
    __shared__ float2 yrow[129];
    __shared__ float ct[256], st[256];
    int t = threadIdx.x;
    if (t < 129) yrow[t] = z[(c * 256 + n1) * 129 + t];
    float a = (2.0f * PI_F / 256.0f) * (float)t;
    ct[t] = cosf(a);
    st[t] = sinf(a);
    __syncthreads();
    float acc = yrow[0].x + ((t & 1) ? -yrow[128].x : yrow[128].x);
    int idx = t;
    for (int k = 1; k <= 127; ++k) {
        float2 yv = yrow[k];
        acc += 2.0f * (yv.x * ct[idx] - yv.y * st[idx]);
        idx = (idx + t) & 255;
    }
    corrected[c * 65536 + n1 * 256 + t] += acc * (1.0f / 256.0f);
}

// ---------------------------------------------------------------------------
extern "C" void kernel_launch(void* const* d_in, const int* in_sizes, int n_in,
                              void* d_out, int out_size, void* d_ws, size_t ws_size,
                              hipStream_t stream)
{
    const float* raw = (const float*)d_in[0];
    const float* ab  = (const float*)d_in[1];
    const float* pw1 = (const float*)d_in[2];  const float* pb1 = (const float*)d_in[3];
    const float* pw2 = (const float*)d_in[4];  const float* pb2 = (const float*)d_in[5];
    const float* pw3 = (const float*)d_in[6];  const float* pb3 = (const float*)d_in[7];
    const float* fw1 = (const float*)d_in[8];  const float* fb1 = (const float*)d_in[9];
    const float* fw2 = (const float*)d_in[10]; const float* fb2 = (const float*)d_in[11];
    const float* fw3 = (const float*)d_in[12]; const float* fb3 = (const float*)d_in[13];
    const float* cw1 = (const float*)d_in[14]; const float* cb1 = (const float*)d_in[15];
    const float* cw2 = (const float*)d_in[16]; const float* cb2 = (const float*)d_in[17];
    const float* cw3 = (const float*)d_in[18]; const float* cb3 = (const float*)d_in[19];
    float* out = (float*)d_out;

    float* Wf = (float*)d_ws;
    float* h1        = Wf;                    // 16,777,216 f
    float* h2        = Wf + 16777216;         //  8,388,608 f region:
    float2* zbuf  = (float2*)h2;              //   528,384 f
    float* fri32  = h2 + 528384;              // 1,081,344 f  (32ch x 256 x 132)
    float* g1     = h2 + 1609728;             // 2,162,688 f  (64ch x 256 x 132)
    float* g2     = h2 + 3772416;             // 2,162,688 f
    float* gf     = h2 + 5935104;             //   270,336 f  (8ch x 256 x 132)
    float* corrected = Wf + 25165824;         //   262,144 f
    float* logits = h1;
    unsigned short* h1b = (unsigned short*)h1;            // 4,194,304 ush
    unsigned short* h2b = h1b + 4194304;                  // 4,194,304 ush
    unsigned short* wp1 = (unsigned short*)(Wf + 25690112);
    unsigned short* wp2 = wp1 + 294912;
    unsigned short* wp3 = wp2 + 294912;                   // 4 x 294,912
    unsigned short* wf1 = wp3 + 4 * 294912;               // 18,432
    unsigned short* wf2 = wf1 + 18432;                    // 36,864
    unsigned short* wf3 = wf2 + 36864;                    // 36,864
    unsigned short* wr2 = wf3 + 36864;                    // 10,240

    dim3 blk(256);

    // weight repacks
    repack_w<<<dim3(288), blk, 0, stream>>>(pw1, wp1, 128, 128, 256, 256);
    repack_w<<<dim3(288), blk, 0, stream>>>(pw2, wp2, 256, 256, 128, 128);
    for (int c = 0; c < 4; ++c)
        repack_w<<<dim3(288), blk, 0, stream>>>(
            pw3 + (size_t)c * 225 * 128 * 9, wp3 + (size_t)c * 294912, 128, 128, 225, 256);
    repack_w<<<dim3(72), blk, 0, stream>>>(fw1, wf1, 8, 32, 64, 64);
    repack_w<<<dim3(144), blk, 0, stream>>>(fw2, wf2, 64, 64, 64, 64);
    repack_w<<<dim3(144), blk, 0, stream>>>(fw3, wf3, 64, 64, 8, 64);
    repack_wr2<<<dim3(40), blk, 0, stream>>>(cw2, wr2);

    // conv1: ab(128) -> h1(256), relu
    conv3_mfma<true><<<dim3(512, 4), blk, 0, stream>>>(
        ab, (const short*)wp1, pb1, h1, 128, 256, 256, 256, 256, 256);
    // conv2: h1(256) -> h2(128), relu
    conv3_mfma<true><<<dim3(512, 2), blk, 0, stream>>>(
        h1, (const short*)wp2, pb2, h2, 256, 128, 128, 256, 256, 256);
    // psf conv + fused softmax/patch per image channel
    for (int c = 0; c < 4; ++c) {
        conv3_mfma<false><<<dim3(512, 4), blk, 0, stream>>>(
            h2, (const short*)(wp3 + (size_t)c * 294912), pb3 + c * 225, logits,
            128, 225, 256, 256, 256, 256);
        softmax_patch_kernel<<<dim3(1024), blk, 0, stream>>>(
            logits, raw + c * 65536, corrected + c * 65536);
    }
    // forward rfft2 (ortho)
    hipMemsetAsync(fri32, 0, (size_t)32 * 256 * 132 * 4, stream);
    rdft_row_kernel<<<dim3(1024), blk, 0, stream>>>(corrected, zbuf);
    dft_col_fwd_kernel<<<dim3(1024), blk, 0, stream>>>(zbuf, fri32);
    // freq-domain convs via MFMA (W=129, RS=132)
    conv3_mfma<true><<<dim3(512, 1), blk, 0, stream>>>(
        fri32, (const short*)wf1, fb1, g1, 32, 64, 64, 256, 129, 132);
    conv3_mfma<true><<<dim3(512, 1), blk, 0, stream>>>(
        g1, (const short*)wf2, fb2, g2, 64, 64, 64, 256, 129, 132);
    conv3_mfma<false><<<dim3(512, 1), blk, 0, stream>>>(
        g2, (const short*)wf3, fb3, gf, 64, 8, 64, 256, 129, 132);
    // inverse irfft2 (ortho), accumulate into corrected
    dft_col_inv_kernel<<<dim3(1024), blk, 0, stream>>>(gf, zbuf);
    irdft_row_add_kernel<<<dim3(1024), blk, 0, stream>>>(zbuf, corrected);
    // per-channel refinement (batched over 4 channels), fused final clip
    refine1_kernel<<<dim3(1024), blk, 0, stream>>>(corrected, cw1, cb1, h1b);
    refine2_mfma<<<dim3(1024), blk, 0, stream>>>(h1b, wr2, cb2, h2b);
    refine3_kernel<<<dim3(1024), blk, 0, stream>>>(h2b, cw3, cb3, raw, out);
}

// Round 6
// 648.653 us; speedup vs baseline: 8.6668x; 1.3573x over previous
//
#include <hip/hip_runtime.h>
#include <hip/hip_bf16.h>
#include <math.h>

#define PI_F 3.14159265358979323846f
// ci16 permutation (involution, swaps bits 2<->3): storage slot s holds channel PERM4(s)
#define PERM4(s) ((((s)&3)) + 8*(((s)>>2)&1) + 4*((s)>>3))

typedef short bfrag __attribute__((ext_vector_type(8)));   // 8 bf16 (4 VGPR)
typedef float f32x4 __attribute__((ext_vector_type(4)));
typedef float f32x16 __attribute__((ext_vector_type(16)));
typedef unsigned short us8 __attribute__((ext_vector_type(8)));

__device__ inline unsigned bf16rne(float x) {
    unsigned u = __builtin_bit_cast(unsigned, x);
    return (u + 0x7fffu + ((u >> 16) & 1u)) >> 16;
}
__device__ inline unsigned packbf2(float a, float b) {
    return bf16rne(a) | (bf16rne(b) << 16);
}
__device__ inline float bf2f(unsigned short u) {
    return __builtin_bit_cast(float, (unsigned)u << 16);
}
// LDS byte addr for (px slot 0..135, g 0..3); 128B row pairs 2 px, 8 units of 16B.
// Balanced across all 8 bank-quads for b128 reads (lanes=px) AND b128 writes.
__device__ inline int lds_u(int px, int g) {
    int row = px >> 1;
    return row * 128 + (((((px & 1) << 2) | g) ^ (row & 7)) << 4);
}

// ---------------------------------------------------------------------------
// MFMA implicit-GEMM 3x3 conv, pad 1, 32x32x16 bf16 MFMA.
// IO: bf16 "blocked" tensors [cb16][256 y][RSg x][16 slots], slot s = ch PERM4(s).
// Block 256 thr = 4 waves (2 co-tiles x 2 px-halves); tile 64 co x 128 px.
// ---------------------------------------------------------------------------
template<bool RELU, bool OUT_BF16>
__global__ __launch_bounds__(256, 3) void conv_v2(
    const unsigned short* __restrict__ inb, const short* __restrict__ wp,
    const float* __restrict__ bias, void* __restrict__ outv,
    int C32, int Cout, int COT, int W, int RSg, int CBmax)
{
    const int tilesx = (W + 127) >> 7;
    const int y  = blockIdx.x / tilesx;
    const int x0 = (blockIdx.x % tilesx) << 7;
    const int t  = threadIdx.x;
    const int l  = t & 63;
    const int col = l & 31, kh = l >> 5;
    const int wv = t >> 6;
    const int wct = wv & 1, wpt = wv >> 1;
    const int ctg = (blockIdx.y << 1) + wct;

    __shared__ __align__(16) unsigned char sB[26112];   // 3 rows x 68 rowpairs x 128B

    f32x16 acc0, acc1;
#pragma unroll
    for (int i = 0; i < 16; ++i) { acc0[i] = 0.f; acc1[i] = 0.f; }

    int ba3[3];
#pragma unroll
    for (int dx = 0; dx < 3; ++dx)
        ba3[dx] = lds_u(wpt * 64 + col + 3 + dx, kh);   // cs=0; cs=1 => ^32; n=1 => +2048

    const bfrag* wA = (const bfrag*)wp;
    const int tstr = C32 * 2 * COT * 64;

    for (int c32 = 0; c32 < C32; ++c32) {
        __syncthreads();
        // stage: 3 rows x 136 px x 4 g-units (16B each), pure copies
        for (int i = t; i < 1632; i += 256) {
            int g = i & 3, rem = i >> 2;
            int px = rem % 136, r = rem / 136;
            int cb = (c32 << 1) + (g >> 1);
            int gy = y + r - 1, gx = x0 - 4 + px;
            uint4 v = make_uint4(0, 0, 0, 0);
            if ((unsigned)gy < 256u && (unsigned)gx < (unsigned)W)
                v = *(const uint4*)(inb + ((((size_t)cb << 8) + gy) * RSg + gx) * 16 + ((i & 1) << 3));
            *(uint4*)(sB + r * 8704 + lds_u(px, g)) = v;
        }
        __syncthreads();

#pragma unroll 1
        for (int cs = 0; cs < 2; ++cs) {
            const int abase = ((c32 * 2 + cs) * COT + ctg) * 64 + l;
            bfrag af[9];
#pragma unroll
            for (int tap = 0; tap < 9; ++tap)
                af[tap] = wA[abase + tap * tstr];
            const int xs = cs << 5;
#pragma unroll
            for (int tap = 0; tap < 9; ++tap) {
                const int dy = tap / 3, dx = tap % 3;
                const unsigned char* rp = sB + dy * 8704;
                bfrag b0 = *(const bfrag*)(rp + (ba3[dx] ^ xs));
                bfrag b1 = *(const bfrag*)(rp + ((ba3[dx] ^ xs) + 2048));
                acc0 = __builtin_amdgcn_mfma_f32_32x32x16_bf16(af[tap], b0, acc0, 0, 0, 0);
                acc1 = __builtin_amdgcn_mfma_f32_32x32x16_bf16(af[tap], b1, acc1, 0, 0, 0);
            }
        }
    }

    // epilogue: C/D col = l&31 (px), row = (reg&3)+8*(reg>>2)+4*kh
    const int xBase = x0 + wpt * 64 + col;
#pragma unroll
    for (int n = 0; n < 2; ++n) {
        int xx = xBase + n * 32;
        if (xx >= W) continue;
        const f32x16 A = n ? acc1 : acc0;
        if (OUT_BF16) {
            unsigned short* ob = (unsigned short*)outv;
#pragma unroll
            for (int rh = 0; rh < 2; ++rh) {
                int cb = ctg * 2 + rh;
                if (cb >= CBmax) continue;
                unsigned wd[4];
#pragma unroll
                for (int jp = 0; jp < 4; ++jp) {
                    float vv[2];
#pragma unroll
                    for (int e = 0; e < 2; ++e) {
                        int j = jp * 2 + e;
                        int co = cb * 16 + (j & 3) + 8 * (j >> 2) + 4 * kh;
                        float bv = (co < Cout) ? bias[co] : 0.f;
                        float v = A[rh * 8 + j] + bv;
                        if (RELU) v = fmaxf(v, 0.f);
                        vv[e] = v;
                    }
                    wd[jp] = packbf2(vv[0], vv[1]);
                }
                *(uint4*)(ob + ((((size_t)cb << 8) + y) * RSg + xx) * 16 + (kh << 3)) =
                    make_uint4(wd[0], wd[1], wd[2], wd[3]);
            }
        } else {
            float* of = (float*)outv;
#pragma unroll
            for (int reg = 0; reg < 16; ++reg) {
                int co = ctg * 32 + (reg & 3) + 8 * (reg >> 2) + 4 * kh;
                if (co < Cout) {
                    float v = A[reg] + bias[co];
                    if (RELU) v = fmaxf(v, 0.f);
                    of[(((size_t)co << 8) + y) * RSg + xx] = v;
                }
            }
        }
    }
}

// Repack fp32 OIHW -> A-frag order for 32x32x16 (PERM on ci within 16-blocks).
__global__ __launch_bounds__(256) void repack_wA(
    const float* __restrict__ w, unsigned short* __restrict__ o,
    int Cin, int C32, int Cout, int COT)
{
    int total = 9 * C32 * 2 * COT * 512;
    for (int i = blockIdx.x * 256 + threadIdx.x; i < total; i += gridDim.x * 256) {
        int j = i & 7;
        int l = (i >> 3) & 63;
        int rest = i >> 9;
        int ct = rest % COT; rest /= COT;
        int cs = rest & 1; rest >>= 1;
        int c32 = rest % C32;
        int tap = rest / C32;
        int co = ct * 32 + (l & 31);
        int s = ((l >> 5) << 3) + j;
        int ci = c32 * 32 + cs * 16 + PERM4(s);
        float v = (co < Cout && ci < Cin) ? w[((size_t)co * Cin + ci) * 9 + tap] : 0.f;
        o[i] = (unsigned short)bf16rne(v);
    }
}

// fp32 NCHW [C][256][256] -> bf16 blocked [CB][y][x][16] with PERM slots
__global__ __launch_bounds__(256) void cvt_blocked(
    const float* __restrict__ src, unsigned short* __restrict__ dst, int C)
{
    int cb = blockIdx.x >> 8;
    int y  = blockIdx.x & 255;
    int x  = threadIdx.x;
    unsigned wd[8];
#pragma unroll
    for (int q = 0; q < 8; ++q) {
        float v[2];
#pragma unroll
        for (int e = 0; e < 2; ++e) {
            int s = q * 2 + e;
            int ci = (cb << 4) + PERM4(s);
            v[e] = (ci < C) ? src[((size_t)ci * 256 + y) * 256 + x] : 0.f;
        }
        wd[q] = packbf2(v[0], v[1]);
    }
    unsigned short* dp = dst + (((size_t)cb << 16) + (y << 8) + x) * 16;
    *(uint4*)dp = make_uint4(wd[0], wd[1], wd[2], wd[3]);
    *(uint4*)(dp + 8) = make_uint4(wd[4], wd[5], wd[6], wd[7]);
}

// ---------------------------------------------------------------------------
// Fused softmax(225) + reflect-patch sum, reading bf16 blocked logits.
// Block = 64 px x 4 tap-subsets (cb mod 4); deferred-max online softmax.
// ---------------------------------------------------------------------------
__global__ __launch_bounds__(256) void softmax_patch3(
    const unsigned short* __restrict__ lg, const float* __restrict__ rawc,
    float* __restrict__ corr)
{
    const int t = threadIdx.x;
    const int sub = t >> 6;
    const int p = blockIdx.x * 64 + (t & 63);
    const int y = p >> 8, x = p & 255;
    __shared__ float sm[256], ss[256], sa[256];

    int x0b = (blockIdx.x << 6) & 255;
    const bool intr = (y >= 7) && (y <= 248) && (x0b >= 7) && (x0b + 63 <= 248);

    float mu = -1e30f, s = 0.f, acc = 0.f;
    for (int ib = 0; ib < 4; ++ib) {
        int cb = sub + ib * 4;
        if (cb >= 15) break;
        const unsigned short* up = lg + ((size_t)cb * 65536 + p) * 16;
        uint4 u0 = *(const uint4*)up;
        uint4 u1 = *(const uint4*)(up + 8);
        unsigned uw[8] = {u0.x, u0.y, u0.z, u0.w, u1.x, u1.y, u1.z, u1.w};
#pragma unroll
        for (int s_ = 0; s_ < 16; ++s_) {
            const int Pc = PERM4(s_);
            int tap = (cb << 4) + Pc;
            if (tap > 224) continue;
            float lv = bf2f((unsigned short)(uw[s_ >> 1] >> ((s_ & 1) << 4)));
            int d = (cb + Pc >= 15) ? 1 : 0;
            int ty = cb + d;
            int tx = cb + Pc - (d ? 15 : 0);
            int gy = y + ty - 7, gx = x + tx - 7;
            if (!intr) {
                gy = gy < 0 ? -gy : (gy > 255 ? 510 - gy : gy);
                gx = gx < 0 ? -gx : (gx > 255 ? 510 - gx : gx);
            }
            float pv = rawc[gy * 256 + gx];
            if (lv > mu + 4.f) {              // deferred-max rescale (rare)
                float rs = __expf(mu - lv);
                s *= rs; acc *= rs; mu = lv;
            }
            float e = __expf(lv - mu);
            s += e; acc += e * pv;
        }
    }
    sm[t] = mu; ss[t] = s; sa[t] = acc;
    __syncthreads();
    if (t < 64) {
#pragma unroll
        for (int i = 1; i < 4; ++i) {
            float mi = sm[i * 64 + t], si = ss[i * 64 + t], ai = sa[i * 64 + t];
            float M = fmaxf(mu, mi);
            float sc0 = __expf(mu - M), sc1 = __expf(mi - M);
            s = s * sc0 + si * sc1;
            acc = acc * sc0 + ai * sc1;
            mu = M;
        }
        corr[p] = acc / s;
    }
}

// ---------------------------------------------------------------------------
// Refinement (unchanged from round 2)
// ---------------------------------------------------------------------------
__global__ __launch_bounds__(256) void repack_wr2(
    const float* __restrict__ cw2, unsigned short* __restrict__ o)
{
    int i = blockIdx.x * 256 + threadIdx.x;
    if (i >= 10240) return;
    int k = i & 31, rest = i >> 5;
    int co = rest & 15;
    int kt = (rest >> 4) % 5;
    int ch = rest / 80;
    int tap = 2 * kt + (k >= 16 ? 1 : 0), ci = k & 15;
    float v = 0.f;
    if (tap < 9) v = cw2[(((size_t)ch * 16 + co) * 16 + ci) * 9 + tap];
    o[i] = (unsigned short)bf16rne(v);
}

__global__ __launch_bounds__(256) void refine1_kernel(
    const float* __restrict__ corrected, const float* __restrict__ cw1,
    const float* __restrict__ cb1, unsigned short* __restrict__ h1b)
{
    const int c = blockIdx.x >> 8;
    const int y = blockIdx.x & 255;
    const int t = threadIdx.x;
    __shared__ float sIn[3][258];
    __shared__ float sW[144];
    __shared__ float sBv[16];
    if (t < 144) sW[t] = cw1[c * 144 + t];
    if (t >= 144 && t < 160) sBv[t - 144] = cb1[c * 16 + (t - 144)];
    for (int i = t; i < 774; i += 256) {
        int r = i / 258, xx = i % 258;
        int gy = y + r - 1, gx = xx - 1;
        sIn[r][xx] = ((unsigned)gy < 256u && (unsigned)gx < 256u)
                   ? corrected[((size_t)c * 256 + gy) * 256 + gx] : 0.f;
    }
    __syncthreads();
    float a[9];
#pragma unroll
    for (int dy = 0; dy < 3; ++dy)
#pragma unroll
        for (int dx = 0; dx < 3; ++dx) a[dy * 3 + dx] = sIn[dy][t + dx];
    unsigned short ov[16];
#pragma unroll
    for (int co = 0; co < 16; ++co) {
        float acc = sBv[co];
#pragma unroll
        for (int tap = 0; tap < 9; ++tap) acc += a[tap] * sW[co * 9 + tap];
        acc = fmaxf(acc, 0.f);
        ov[co] = (unsigned short)bf16rne(acc);
    }
    unsigned short* op = h1b + ((((size_t)c * 256 + y) * 256 + t) << 4);
    *(uint4*)op = *(uint4*)ov;
    *(uint4*)(op + 8) = *(uint4*)(ov + 8);
}

__global__ __launch_bounds__(256) void refine2_mfma(
    const unsigned short* __restrict__ h1b, const unsigned short* __restrict__ wr2,
    const float* __restrict__ cb2, unsigned short* __restrict__ h2b)
{
    const int c = blockIdx.x >> 8;
    const int y = blockIdx.x & 255;
    const int t = threadIdx.x;
    const int l15 = t & 15, lg = (t >> 4) & 3, wv = t >> 6;

    __shared__ __align__(16) unsigned char sA[3 * 258 * 32];

    for (int i = t; i < 1548; i += 256) {
        int r = i / 516, u = i % 516;
        int px = u >> 1, half = u & 1;
        int gy = y + r - 1, gx = px - 1;
        uint4 v = make_uint4(0, 0, 0, 0);
        if ((unsigned)gy < 256u && (unsigned)gx < 256u)
            v = *(const uint4*)(h1b + ((((size_t)c * 256 + gy) * 256 + gx) << 4) + (half << 3));
        *(uint4*)(sA + r * 8256 + px * 32 + ((half ^ ((px >> 2) & 1)) << 4)) = v;
    }
    __syncthreads();

    f32x4 acc[4];
#pragma unroll
    for (int n = 0; n < 4; ++n) acc[n] = (f32x4){0.f, 0.f, 0.f, 0.f};
    const bfrag* wf = (const bfrag*)(wr2 + (size_t)c * 2560);
    const int strip = wv * 64;
#pragma unroll
    for (int kt = 0; kt < 5; ++kt) {
        bfrag a = wf[(kt * 16 + l15) * 4 + lg];
        int tap1 = 2 * kt + 1; if (tap1 > 8) tap1 = 8;
        int tap = (lg < 2) ? (2 * kt) : tap1;
        int dy = tap / 3, dx = tap % 3;
#pragma unroll
        for (int n = 0; n < 4; ++n) {
            int pxs = strip + n * 16 + l15 + dx;
            bfrag b = *(const bfrag*)(sA + dy * 8256 + pxs * 32 +
                                      (((lg & 1) ^ ((pxs >> 2) & 1)) << 4));
            acc[n] = __builtin_amdgcn_mfma_f32_16x16x32_bf16(a, b, acc[n], 0, 0, 0);
        }
    }

#pragma unroll
    for (int n = 0; n < 4; ++n) {
        int px = strip + n * 16 + l15;
        unsigned short ov[4];
#pragma unroll
        for (int r = 0; r < 4; ++r) {
            int co = lg * 4 + r;
            float v = acc[n][r] + cb2[c * 16 + co];
            v = fmaxf(v, 0.f);
            ov[r] = (unsigned short)bf16rne(v);
        }
        *(ushort4*)(h2b + ((((size_t)c * 256 + y) * 256 + px) << 4) + lg * 4) = *(ushort4*)ov;
    }
}

__global__ __launch_bounds__(256) void refine3_kernel(
    const unsigned short* __restrict__ h2b, const float* __restrict__ cw3,
    const float* __restrict__ cb3, const float* __restrict__ raw,
    float* __restrict__ out)
{
    const int c = blockIdx.x >> 8;
    const int y = blockIdx.x & 255;
    const int t = threadIdx.x;
    __shared__ __align__(16) unsigned char sA[3 * 258 * 32];
    __shared__ float sW[144];
    if (t < 144) sW[t] = cw3[c * 144 + t];
    for (int i = t; i < 1548; i += 256) {
        int r = i / 516, u = i % 516;
        int px = u >> 1, half = u & 1;
        int gy = y + r - 1, gx = px - 1;
        uint4 v = make_uint4(0, 0, 0, 0);
        if ((unsigned)gy < 256u && (unsigned)gx < 256u)
            v = *(const uint4*)(h2b + ((((size_t)c * 256 + gy) * 256 + gx) << 4) + (half << 3));
        *(uint4*)(sA + r * 8256 + px * 32 + ((half ^ ((px >> 2) & 1)) << 4)) = v;
    }
    __syncthreads();
    float acc = cb3[c];
#pragma unroll
    for (int tap = 0; tap < 9; ++tap) {
        int dy = tap / 3, dx = tap % 3;
        int px = t + dx;
        const unsigned char* p = sA + dy * 8256 + px * 32;
        int sw = ((px >> 2) & 1) << 4;
        us8 h0 = *(const us8*)(p + (sw ^ 0));
        us8 h1 = *(const us8*)(p + (sw ^ 16));
#pragma unroll
        for (int j = 0; j < 8; ++j) acc += bf2f(h0[j]) * sW[j * 9 + tap];
#pragma unroll
        for (int j = 0; j < 8; ++j) acc += bf2f(h1[j]) * sW[(8 + j) * 9 + tap];
    }
    size_t idx = ((size_t)c * 256 + y) * 256 + t;
    float v = raw[idx] + acc;
    out[idx] = fminf(fmaxf(v, 0.f), 1.f);
}

// ---------------------------------------------------------------------------
// DFT kernels
// ---------------------------------------------------------------------------
__global__ __launch_bounds__(256) void rdft_row_kernel(
    const float* __restrict__ x, float2* __restrict__ z)
{
    int cy = blockIdx.x;
    __shared__ float row[256];
    __shared__ float ct[256], st[256];
    int t = threadIdx.x;
    row[t] = x[cy * 256 + t];
    float a = (2.0f * PI_F / 256.0f) * (float)t;
    ct[t] = cosf(a);
    st[t] = sinf(a);
    __syncthreads();
    if (t < 129) {
        float re = 0.f, im = 0.f;
        int idx = 0;
        for (int n = 0; n < 256; ++n) {
            float v = row[n];
            re += v * ct[idx];
            im -= v * st[idx];
            idx = (idx + t) & 255;
        }
        z[cy * 129 + t] = make_float2(re, im);
    }
}

// writes blocked bf16 fri16 (cb0: slots c -> re, 8+c -> im); rest pre-zeroed
__global__ __launch_bounds__(256) void dft_col_fwd2(
    const float2* __restrict__ z, unsigned short* __restrict__ fri16)
{
    int c  = blockIdx.x >> 8;
    int k1 = blockIdx.x & 255;
    __shared__ float ct[256], st[256];
    int t = threadIdx.x;
    float a = (2.0f * PI_F / 256.0f) * (float)t;
    ct[t] = cosf(a);
    st[t] = sinf(a);
    __syncthreads();
    if (t < 129) {
        float re = 0.f, im = 0.f;
        int idx = 0;
        for (int n1 = 0; n1 < 256; ++n1) {
            float2 zv = z[(c * 256 + n1) * 129 + t];
            float cw = ct[idx], sw = st[idx];
            re += zv.x * cw + zv.y * sw;
            im += zv.y * cw - zv.x * sw;
            idx = (idx + k1) & 255;
        }
        const float sc = 1.0f / 256.0f;
        size_t base = ((size_t)k1 * 132 + t) * 16;
        fri16[base + c]     = (unsigned short)bf16rne(re * sc);
        fri16[base + 8 + c] = (unsigned short)bf16rne(im * sc);
    }
}

__global__ __launch_bounds__(256) void dft_col_inv_kernel(
    const float* __restrict__ g, float2* __restrict__ z)
{
    int c  = blockIdx.x >> 8;
    int n1 = blockIdx.x & 255;
    __shared__ float ct[256], st[256];
    int t = threadIdx.x;
    float a = (2.0f * PI_F / 256.0f) * (float)t;
    ct[t] = cosf(a);
    st[t] = sinf(a);
    __syncthreads();
    if (t < 129) {
        float re = 0.f, im = 0.f;
        int idx = 0;
        for (int k1 = 0; k1 < 256; ++k1) {
            float gr = g[((size_t)c * 256 + k1) * 132 + t];
            float gi = g[((size_t)(4 + c) * 256 + k1) * 132 + t];
            float cw = ct[idx], sw = st[idx];
            re += gr * cw - gi * sw;
            im += gi * cw + gr * sw;
            idx = (idx + n1) & 255;
        }
        z[(c * 256 + n1) * 129 + t] = make_float2(re, im);
    }
}

__global__ __launch_bounds__(256) void irdft_row_add_kernel(
    const float2* __restrict__ z, float* __restrict__ corrected)
{
    int c  = blockIdx.x >> 8;
    int n1 = blockIdx.x & 255;
    __shared__ float2 yrow[129];
    __shared__ float ct[256], st[256];
    int t = threadIdx.x;
    if (t < 129) yrow[t] = z[(c * 256 + n1) * 129 + t];
    float a = (2.0f * PI_F / 256.0f) * (float)t;
    ct[t] = cosf(a);
    st[t] = sinf(a);
    __syncthreads();
    float acc = yrow[0].x + ((t & 1) ? -yrow[128].x : yrow[128].x);
    int idx = t;
    for (int k = 1; k <= 127; ++k) {
        float2 yv = yrow[k];
        acc += 2.0f * (yv.x * ct[idx] - yv.y * st[idx]);
        idx = (idx + t) & 255;
    }
    corrected[c * 65536 + n1 * 256 + t] += acc * (1.0f / 256.0f);
}

// ---------------------------------------------------------------------------
extern "C" void kernel_launch(void* const* d_in, const int* in_sizes, int n_in,
                              void* d_out, int out_size, void* d_ws, size_t ws_size,
                              hipStream_t stream)
{
    const float* raw = (const float*)d_in[0];
    const float* ab  = (const float*)d_in[1];
    const float* pw1 = (const float*)d_in[2];  const float* pb1 = (const float*)d_in[3];
    const float* pw2 = (const float*)d_in[4];  const float* pb2 = (const float*)d_in[5];
    const float* pw3 = (const float*)d_in[6];  const float* pb3 = (const float*)d_in[7];
    const float* fw1 = (const float*)d_in[8];  const float* fb1 = (const float*)d_in[9];
    const float* fw2 = (const float*)d_in[10]; const float* fb2 = (const float*)d_in[11];
    const float* fw3 = (const float*)d_in[12]; const float* fb3 = (const float*)d_in[13];
    const float* cw1 = (const float*)d_in[14]; const float* cb1 = (const float*)d_in[15];
    const float* cw2 = (const float*)d_in[16]; const float* cb2 = (const float*)d_in[17];
    const float* cw3 = (const float*)d_in[18]; const float* cb3 = (const float*)d_in[19];
    float* out = (float*)d_out;

    char* B = (char*)d_ws;
    unsigned short* h1b     = (unsigned short*)(B);              // 33,554,432 B (16 cb)
    unsigned short* logits16 = h1b;                              // alias (after conv2)
    unsigned short* h2b     = (unsigned short*)(B + 33554432);   // 16,777,216 B (8 cb)
    unsigned short* h1r     = (unsigned short*)(B + 33554432);   // alias (after psf)
    unsigned short* h2r     = (unsigned short*)(B + 41943040);
    float* corrected = (float*)(B + 50331648);                   // 1,048,576 B
    float2* zbuf     = (float2*)(B + 51380224);                  // 2,113,536 B
    unsigned short* fri16 = (unsigned short*)(B + 53493760);     // 2,162,688 B (2 cb, RS 132)
    unsigned short* g1b   = (unsigned short*)(B + 55656448);     // 4,325,376 B (4 cb)
    unsigned short* g2b   = (unsigned short*)(B + 59981824);     // 4,325,376 B
    float* gf        = (float*)(B + 64307200);                   // 1,081,344 B
    unsigned short* rw1  = (unsigned short*)(B + 65388544);      // 589,824 B
    unsigned short* rw2  = (unsigned short*)(B + 65978368);      // 589,824 B
    unsigned short* rw3  = (unsigned short*)(B + 66568192);      // 4 x 589,824 B
    unsigned short* rwf1 = (unsigned short*)(B + 68927488);      // 36,864 B
    unsigned short* rwf2 = (unsigned short*)(B + 68964352);      // 73,728 B
    unsigned short* rwf3 = (unsigned short*)(B + 69038080);      // 73,728 B
    unsigned short* wr2r = (unsigned short*)(B + 69111808);      // 20,480 B
    unsigned short* ab16 = (unsigned short*)(B + 69132288);      // 16,777,216 B

    dim3 blk(256);

    // weight repacks + input conversion
    repack_wA<<<512, blk, 0, stream>>>(pw1, rw1, 128, 4, 256, 8);
    repack_wA<<<512, blk, 0, stream>>>(pw2, rw2, 256, 8, 128, 4);
    for (int c = 0; c < 4; ++c)
        repack_wA<<<512, blk, 0, stream>>>(
            pw3 + (size_t)c * 225 * 128 * 9, rw3 + (size_t)c * 294912, 128, 4, 225, 8);
    repack_wA<<<64, blk, 0, stream>>>(fw1, rwf1, 8, 1, 64, 2);
    repack_wA<<<128, blk, 0, stream>>>(fw2, rwf2, 64, 2, 64, 2);
    repack_wA<<<128, blk, 0, stream>>>(fw3, rwf3, 64, 2, 8, 2);
    repack_wr2<<<40, blk, 0, stream>>>(cw2, wr2r);
    cvt_blocked<<<2048, blk, 0, stream>>>(ab, ab16, 128);

    // conv1: ab16(128) -> h1b(256), relu
    conv_v2<true, true><<<dim3(512, 4), blk, 0, stream>>>(
        ab16, (const short*)rw1, pb1, h1b, 4, 256, 8, 256, 256, 16);
    // conv2: h1b(256) -> h2b(128), relu
    conv_v2<true, true><<<dim3(512, 2), blk, 0, stream>>>(
        h1b, (const short*)rw2, pb2, h2b, 8, 128, 4, 256, 256, 8);
    // psf conv + fused softmax/patch per image channel
    for (int c = 0; c < 4; ++c) {
        conv_v2<false, true><<<dim3(512, 4), blk, 0, stream>>>(
            h2b, (const short*)(rw3 + (size_t)c * 294912), pb3 + c * 225, logits16,
            4, 225, 8, 256, 256, 15);
        softmax_patch3<<<1024, blk, 0, stream>>>(
            logits16, raw + c * 65536, corrected + c * 65536);
    }
    // forward rfft2 (ortho)
    rdft_row_kernel<<<1024, blk, 0, stream>>>(corrected, zbuf);
    hipMemsetAsync(fri16, 0, 2162688, stream);
    dft_col_fwd2<<<1024, blk, 0, stream>>>(zbuf, fri16);
    // freq-domain convs (W=129, RS=132)
    conv_v2<true, true><<<dim3(512, 1), blk, 0, stream>>>(
        fri16, (const short*)rwf1, fb1, g1b, 1, 64, 2, 129, 132, 4);
    conv_v2<true, true><<<dim3(512, 1), blk, 0, stream>>>(
        g1b, (const short*)rwf2, fb2, g2b, 2, 64, 2, 129, 132, 4);
    conv_v2<false, false><<<dim3(512, 1), blk, 0, stream>>>(
        g2b, (const short*)rwf3, fb3, gf, 2, 8, 2, 129, 132, 0);
    // inverse irfft2 (ortho), accumulate into corrected
    dft_col_inv_kernel<<<1024, blk, 0, stream>>>(gf, zbuf);
    irdft_row_add_kernel<<<1024, blk, 0, stream>>>(zbuf, corrected);
    // per-channel refinement, fused final clip
    refine1_kernel<<<1024, blk, 0, stream>>>(corrected, cw1, cb1, h1r);
    refine2_mfma<<<1024, blk, 0, stream>>>(h1r, wr2r, cb2, h2r);
    refine3_kernel<<<1024, blk, 0, stream>>>(h2r, cw3, cb3, raw, out);
}